// Round 17
// baseline (374.404 us; speedup 1.0000x reference)
//
#include <hip/hip_runtime.h>

typedef __bf16 bf16x8 __attribute__((ext_vector_type(8)));
typedef float f32x4 __attribute__((ext_vector_type(4)));

__device__ __forceinline__ unsigned short f2bf(float f) {
    unsigned int u = __float_as_uint(f);
    unsigned int r = (u + 0x7FFFu + ((u >> 16) & 1u)) >> 16;
    return (unsigned short)r;
}

__device__ __forceinline__ void gload16(const void* g, void* l) {
    __builtin_amdgcn_global_load_lds(
        (const __attribute__((address_space(1))) unsigned int*)g,
        (__attribute__((address_space(3))) unsigned int*)l, 16, 0, 0);
}

__device__ __forceinline__ void barrier_raw() {
    asm volatile("" ::: "memory");
    __builtin_amdgcn_s_barrier();
    asm volatile("" ::: "memory");
}

__device__ __forceinline__ void vmwait0() {
    asm volatile("s_waitcnt vmcnt(0)" ::: "memory");
}

__device__ __forceinline__ float gelu_fast(float u) {
    float z = 1.595769122f * u + 0.071354816f * u * u * u;
    return u / (1.f + __expf(-z));
}

// ======== merged prep: f2b4(Wq) | f2b4(Wo) | transpose(w1) | transpose(w2) | ada_part ========
__global__ __launch_bounds__(256) void prep_all(const float* __restrict__ in_proj_w,
                                                const float* __restrict__ out_proj_w,
                                                const float* __restrict__ w1,
                                                const float* __restrict__ w2,
                                                const float* __restrict__ c,
                                                const float* __restrict__ m_ada_w,
                                                const float* __restrict__ f_ada_w,
                                                unsigned short* __restrict__ Wq,
                                                unsigned short* __restrict__ Wo,
                                                unsigned short* __restrict__ W1t,
                                                unsigned short* __restrict__ W2t,
                                                float* __restrict__ part,
                                                float* __restrict__ part2) {
    int z = blockIdx.x;
    if (z < 4096) {
        const float* in = (z < 3072) ? in_proj_w : out_proj_w;
        unsigned short* out = (z < 3072) ? Wq : Wo;
        int zz = (z < 3072) ? z : z - 3072;
        size_t i = ((size_t)zz * 256 + threadIdx.x) * 4;
        float4 v = *(const float4*)(in + i);
        ushort4 o;
        o.x = f2bf(v.x); o.y = f2bf(v.y); o.z = f2bf(v.z); o.w = f2bf(v.w);
        *(ushort4*)(out + i) = o;
    } else if (z < 12288) {
        __shared__ float tile[32][33];
        int zz = z - 4096;
        const float* in; unsigned short* out; int R, C, bx, by;
        if (zz < 4096) { in = w1; out = W1t; R = 1024; C = 4096; bx = zz & 127; by = zz >> 7; }
        else { zz -= 4096; in = w2; out = W2t; R = 4096; C = 1024; bx = zz & 31; by = zz >> 5; }
        int r0 = by * 32, c0 = bx * 32;
        int tx = threadIdx.x & 31, ty = threadIdx.x >> 5;
#pragma unroll
        for (int i = 0; i < 4; i++) {
            int r = ty + i * 8;
            tile[r][tx] = in[(size_t)(r0 + r) * C + c0 + tx];
        }
        __syncthreads();
#pragma unroll
        for (int i = 0; i < 4; i++) {
            int r = ty + i * 8;
            out[(size_t)(c0 + r) * R + r0 + tx] = f2bf(tile[tx][r]);
        }
    } else {
        __shared__ float sc[8 * 64];
        int zz = z - 12288;
        int jb = zz % 12;
        int rest = zz / 12;
        int kb = rest & 15, sel = rest >> 4;
        const float* W = sel ? f_ada_w : m_ada_w;
        float* partial = sel ? part2 : part;
        int kc = kb * 64;
        for (int i = threadIdx.x; i < 512; i += 256) {
            int b = i >> 6, k = i & 63;
            float cv = c[b * 1024 + kc + k];
            sc[i] = cv / (1.f + __expf(-cv));
        }
        __syncthreads();
        int j = jb * 256 + threadIdx.x;
        float acc[8] = {0, 0, 0, 0, 0, 0, 0, 0};
        for (int k = 0; k < 64; k++) {
            float w = W[(size_t)(kc + k) * 3072 + j];
#pragma unroll
            for (int b = 0; b < 8; b++) acc[b] += sc[b * 64 + k] * w;
        }
#pragma unroll
        for (int b = 0; b < 8; b++) partial[((size_t)kb * 8 + b) * 3072 + j] = acc[b];
    }
}

__global__ __launch_bounds__(256) void ada_reduce(const float* __restrict__ p0,
                                                  const float* __restrict__ p1,
                                                  const float* __restrict__ b0,
                                                  const float* __restrict__ b1,
                                                  float* __restrict__ o0,
                                                  float* __restrict__ o1) {
    const float* partial = blockIdx.y ? p1 : p0;
    const float* bias = blockIdx.y ? b1 : b0;
    float* out = blockIdx.y ? o1 : o0;
    int idx = blockIdx.x * 256 + threadIdx.x;
    int b = idx / 3072;
    int jj = idx - b * 3072;
    float s = bias[jj];
#pragma unroll
    for (int ch = 0; ch < 16; ch++) s += partial[((size_t)ch * 8 + b) * 3072 + jj];
    out[idx] = s;
}

// -------- LN + adaLN modulate: fp32 row -> bf16 row --------
__global__ __launch_bounds__(256) void ln_mod_kernel(const float* __restrict__ x,
                                                     const float* __restrict__ gamma,
                                                     const float* __restrict__ beta,
                                                     const float* __restrict__ mods,
                                                     unsigned short* __restrict__ out) {
    int row = blockIdx.x;
    int b = row >> 10;
    float4 v = ((const float4*)(x + (size_t)row * 1024))[threadIdx.x];
    float s = v.x + v.y + v.z + v.w;
    float s2 = v.x * v.x + v.y * v.y + v.z * v.z + v.w * v.w;
#pragma unroll
    for (int d = 1; d < 64; d <<= 1) { s += __shfl_xor(s, d); s2 += __shfl_xor(s2, d); }
    __shared__ float red[8];
    int lane = threadIdx.x & 63, wid = threadIdx.x >> 6;
    if (lane == 0) { red[wid] = s; red[4 + wid] = s2; }
    __syncthreads();
    float S = red[0] + red[1] + red[2] + red[3];
    float S2 = red[4] + red[5] + red[6] + red[7];
    float mu = S * (1.f / 1024.f);
    float var = S2 * (1.f / 1024.f) - mu * mu;
    float rs = rsqrtf(var + 1e-6f);
    const float* mrow = mods + b * 3072;
    int j0 = threadIdx.x * 4;
    float hv[4] = {v.x, v.y, v.z, v.w};
    ushort4 o;
    unsigned short* op = (unsigned short*)&o;
#pragma unroll
    for (int i = 0; i < 4; i++) {
        int j = j0 + i;
        float hh = (hv[i] - mu) * rs * gamma[j] + beta[j];
        hh = hh * (1.f + mrow[1024 + j]) + mrow[j];
        op[i] = f2bf(hh);
    }
    *(ushort4*)(out + (size_t)row * 1024 + j0) = o;
}

// ============ big-tile multi-block GEMM, compile-time addressing ============
// BM=BN=256, BK=32, 512 thr (8 waves 2x4, per-wave 128x64).  LDS 64KB (2 dbuf)
// -> 2 blocks/CU.  K-loop unrolled x2 (compile-time dbuf index); 64B LDS rows,
// (row>>1)&3 16B-slot XOR (0 conflicts), source pre-swizzled.
// EP: 0 = +bias -> bf16 (cols>=2048 write V^T to vt), 2 = gelu(acc+bias) -> bf16
template <int EP>
__global__ __launch_bounds__(512, 2) void gemm9(const unsigned short* __restrict__ A,
                                                const unsigned short* __restrict__ Bt,
                                                int N, int K, int nx,
                                                const float* __restrict__ bias,
                                                unsigned short* __restrict__ outb,
                                                unsigned short* __restrict__ vt) {
    constexpr int TE = 256 * 32;
    extern __shared__ __align__(16) char smem[];
    __bf16* As = (__bf16*)smem;
    __bf16* Bs = As + 2 * TE;

    int tid = threadIdx.x, lane = tid & 63, wid = tid >> 6;
    int wr = wid >> 2, wc = wid & 3;
    int t = lane & 15, g = lane >> 4;
    int xk2 = ((t >> 1) & 3) * 8;

    int nwg = gridDim.x, chunk = nwg >> 3;
    int swz = (blockIdx.x & 7) * chunk + (blockIdx.x >> 3);
    int bx = swz % nx, by = swz / nx;
    int rowA0 = by * 256, colB0 = bx * 256;

    int rin = tid >> 2, cblk = tid & 3;
    int scol = (cblk ^ ((rin >> 1) & 3)) * 8;

    const __bf16* a_rd = As + (wr * 128 + t) * 32 + ((g * 8) ^ xk2);
    const __bf16* b_rd = Bs + (wc * 64 + t) * 32 + ((g * 8) ^ xk2);
    __bf16* a_wr = As + rin * 32 + cblk * 8;
    __bf16* b_wr = Bs + rin * 32 + cblk * 8;
    const unsigned short* pa = A + (size_t)(rowA0 + rin) * K + scol;
    const unsigned short* pb = Bt + (size_t)(colB0 + rin) * K + scol;
    const size_t aStep = (size_t)128 * K;

    f32x4 acc[8][4];
#pragma unroll
    for (int m = 0; m < 8; m++)
#pragma unroll
        for (int n = 0; n < 4; n++) acc[m][n] = (f32x4){0.f, 0.f, 0.f, 0.f};

    int NT = K >> 5;
    gload16(pa, a_wr); gload16(pa + aStep, a_wr + 4096);
    gload16(pb, b_wr); gload16(pb + aStep, b_wr + 4096);
    vmwait0();
    barrier_raw();

#define G9_BODY(CUR)                                                                     \
    {                                                                                    \
        constexpr int NB = CUR ^ 1;                                                      \
        bool more = (kt + 1) < NT;                                                       \
        const unsigned short* sa = pa + (kt + 1) * 32;                                   \
        const unsigned short* sb = pb + (kt + 1) * 32;                                   \
        bf16x8 b[4], a0[4];                                                              \
        _Pragma("unroll")                                                                \
        for (int n = 0; n < 4; n++) b[n] = *(const bf16x8*)(b_rd + CUR * TE + n * 512);  \
        _Pragma("unroll")                                                                \
        for (int m = 0; m < 4; m++) a0[m] = *(const bf16x8*)(a_rd + CUR * TE + m * 512); \
        if (more) { gload16(sa, a_wr + NB * TE); gload16(sa + aStep, a_wr + NB * TE + 4096); } \
        __builtin_amdgcn_s_setprio(1);                                                   \
        _Pragma("unroll")                                                                \
        for (int m = 0; m < 4; m++)                                                      \
            _Pragma("unroll")                                                            \
            for (int n = 0; n < 4; n++)                                                  \
                acc[m][n] = __builtin_amdgcn_mfma_f32_16x16x32_bf16(a0[m], b[n], acc[m][n], 0, 0, 0); \
        __builtin_amdgcn_s_setprio(0);                                                   \
        bf16x8 a1[4];                                                                    \
        _Pragma("unroll")                                                                \
        for (int m = 0; m < 4; m++)                                                      \
            a1[m] = *(const bf16x8*)(a_rd + CUR * TE + 2048 + m * 512);                  \
        if (more) { gload16(sb, b_wr + NB * TE); gload16(sb + aStep, b_wr + NB * TE + 4096); } \
        __builtin_amdgcn_s_setprio(1);                                                   \
        _Pragma("unroll")                                                                \
        for (int m = 0; m < 4; m++)                                                      \
            _Pragma("unroll")                                                            \
            for (int n = 0; n < 4; n++)                                                  \
                acc[4 + m][n] = __builtin_amdgcn_mfma_f32_16x16x32_bf16(a1[m], b[n], acc[4 + m][n], 0, 0, 0); \
        __builtin_amdgcn_s_setprio(0);                                                   \
        if (more) { vmwait0(); barrier_raw(); }                                          \
    }

#pragma unroll 1
    for (int kt = 0; kt < NT; kt += 2) {
        G9_BODY(0)
        ++kt;
        G9_BODY(1)
        --kt;
    }
#undef G9_BODY

    int col0 = colB0 + wc * 64;
    bool vpart = (EP == 0) && (colB0 >= 2048);
#pragma unroll
    for (int m = 0; m < 8; m++)
#pragma unroll
        for (int n = 0; n < 4; n++) {
            int col = col0 + n * 16 + t;
            if (EP == 0 && vpart) {
                int hcol = col - 2048;
                int hh = hcol >> 7, dd = hcol & 127;
                int row0 = rowA0 + wr * 128 + m * 16 + g * 4;
                int bb = row0 >> 10;
                int ntok = row0 & 1023;
                float bs = bias[col];
                ushort4 vv;
                vv.x = f2bf(acc[m][n][0] + bs);
                vv.y = f2bf(acc[m][n][1] + bs);
                vv.z = f2bf(acc[m][n][2] + bs);
                vv.w = f2bf(acc[m][n][3] + bs);
                *(ushort4*)(vt + (((size_t)(bb * 8 + hh) * 128 + dd) * 1024 + ntok)) = vv;
            } else {
#pragma unroll
                for (int r = 0; r < 4; r++) {
                    int row = rowA0 + wr * 128 + m * 16 + g * 4 + r;
                    float v = acc[m][n][r];
                    if (EP == 0) {
                        outb[(size_t)row * N + col] = f2bf(v + bias[col]);
                    } else {
                        outb[(size_t)row * N + col] = f2bf(gelu_fast(v + bias[col]));
                    }
                }
            }
        }
}

// ============ NF2 GEMM, compile-time addressing: BM=128, BN=128, BK=32 ============
template <int EP>
__global__ __launch_bounds__(256, 4) void gemmo(const unsigned short* __restrict__ A,
                                                const unsigned short* __restrict__ Bt,
                                                int N, int K, int nx,
                                                const float* __restrict__ bias,
                                                const float* __restrict__ xres,
                                                const float* __restrict__ mods,
                                                float* __restrict__ outf) {
    constexpr int TE = 128 * 32;
    extern __shared__ __align__(16) char smem[];
    __bf16* As = (__bf16*)smem;
    __bf16* Bs = As + 2 * TE;

    int tid = threadIdx.x, lane = tid & 63, wid = tid >> 6;
    int wr = wid >> 1, wc = wid & 1;
    int t = lane & 15, g = lane >> 4;
    int xk2 = ((t >> 1) & 3) * 8;

    int nwg = gridDim.x, chunk = nwg >> 3;
    int swz = (blockIdx.x & 7) * chunk + (blockIdx.x >> 3);
    int bx = swz % nx, by = swz / nx;
    int rowA0 = by * 128, colB0 = bx * 128;

    int rin = tid >> 2, cblk = tid & 3;
    int scol = (cblk ^ ((rin >> 1) & 3)) * 8;

    const __bf16* a_rd = As + (wr * 64 + t) * 32 + ((g * 8) ^ xk2);
    const __bf16* b_rd = Bs + (wc * 64 + t) * 32 + ((g * 8) ^ xk2);
    __bf16* a_wr = As + rin * 32 + cblk * 8;
    __bf16* b_wr = Bs + rin * 32 + cblk * 8;
    const unsigned short* pa = A + (size_t)(rowA0 + rin) * K + scol;
    const unsigned short* pb = Bt + (size_t)(colB0 + rin) * K + scol;
    const size_t hStep = (size_t)64 * K;

    f32x4 acc[4][4];
#pragma unroll
    for (int m = 0; m < 4; m++)
#pragma unroll
        for (int n = 0; n < 4; n++) acc[m][n] = (f32x4){0.f, 0.f, 0.f, 0.f};

    int NT = K >> 5;
    gload16(pa, a_wr); gload16(pa + hStep, a_wr + 2048);
    gload16(pb, b_wr); gload16(pb + hStep, b_wr + 2048);
    vmwait0();
    barrier_raw();

#define GO_BODY(CUR)                                                                     \
    {                                                                                    \
        constexpr int NB = CUR ^ 1;                                                      \
        bool more = (kt + 1) < NT;                                                       \
        const unsigned short* sa = pa + (kt + 1) * 32;                                   \
        const unsigned short* sb = pb + (kt + 1) * 32;                                   \
        if (more) {                                                                      \
            gload16(sa, a_wr + NB * TE); gload16(sa + hStep, a_wr + NB * TE + 2048);     \
            gload16(sb, b_wr + NB * TE); gload16(sb + hStep, b_wr + NB * TE + 2048);     \
        }                                                                                \
        bf16x8 a[4], b[4];                                                               \
        _Pragma("unroll")                                                                \
        for (int m = 0; m < 4; m++) a[m] = *(const bf16x8*)(a_rd + CUR * TE + m * 512);  \
        _Pragma("unroll")                                                                \
        for (int n = 0; n < 4; n++) b[n] = *(const bf16x8*)(b_rd + CUR * TE + n * 512);  \
        __builtin_amdgcn_s_setprio(1);                                                   \
        _Pragma("unroll")                                                                \
        for (int m = 0; m < 4; m++)                                                      \
            _Pragma("unroll")                                                            \
            for (int n = 0; n < 4; n++)                                                  \
                acc[m][n] = __builtin_amdgcn_mfma_f32_16x16x32_bf16(a[m], b[n], acc[m][n], 0, 0, 0); \
        __builtin_amdgcn_s_setprio(0);                                                   \
        if (more) { vmwait0(); barrier_raw(); }                                          \
    }

#pragma unroll 1
    for (int kt = 0; kt < NT; kt += 2) {
        GO_BODY(0)
        ++kt;
        GO_BODY(1)
        --kt;
    }
#undef GO_BODY

    int row0 = rowA0 + wr * 64, col0 = colB0 + wc * 64;
#pragma unroll
    for (int m = 0; m < 4; m++)
#pragma unroll
        for (int n = 0; n < 4; n++) {
            int col = col0 + n * 16 + t;
#pragma unroll
            for (int r = 0; r < 4; r++) {
                int row = row0 + m * 16 + g * 4 + r;
                float v = acc[m][n][r];
                int bb = row >> 10;
                float gt = mods[bb * 3072 + 2048 + col];
                if (EP == 1) {
                    outf[(size_t)row * 1024 + col] =
                        xres[(size_t)row * 1024 + col] + gt * (v + bias[col]);
                } else {
                    outf[(size_t)row * 1024 + col] += gt * (v + bias[col]);
                }
            }
        }
}

// ======== flash attention, swapped-QK^T in-register softmax + defer-max ========
__global__ __launch_bounds__(512, 4) void attn_kernel(const unsigned short* __restrict__ qkv,
                                                      const unsigned short* __restrict__ vt,
                                                      unsigned short* __restrict__ o) {
    extern __shared__ __align__(16) char asmem[];
    __bf16* Ks = (__bf16*)asmem;
    __bf16* Vts = Ks + 2 * 64 * 128;

    int bid = blockIdx.x;
    int logical = (bid & 7) * 64 + (bid >> 3);
    int q0 = (logical & 7) * 128;
    int bh = logical >> 3;
    int b = bh >> 3, h = bh & 7;
    int tid = threadIdx.x, lane = tid & 63, w = tid >> 6;
    int t = lane & 15, g = lane >> 4;
    int swzt = (t & 7) << 4;

    const unsigned short* qbase = qkv + (size_t)(b * 1024) * 3072 + h * 128;
    int qrow = q0 + w * 16 + t;
    bf16x8 qf[4];
#pragma unroll
    for (int ks = 0; ks < 4; ks++)
        qf[ks] = *(const bf16x8*)(qbase + (size_t)qrow * 3072 + ks * 32 + g * 8);

    f32x4 Oa[8];
#pragma unroll
    for (int n = 0; n < 8; n++) Oa[n] = (f32x4){0.f, 0.f, 0.f, 0.f};
    float m_r = -1e30f, l_r = 0.f;
    const float scale = 0.08838834764831845f;

    int krow = tid >> 4;
    int ksrc = (((tid & 15) * 16) ^ ((krow & 7) << 4)) >> 1;
    int vrow = tid >> 3;
    int vsrc = (((tid & 7) * 16) ^ ((vrow & 7) << 4)) >> 1;
    const unsigned short* vtg = vt + (size_t)bh * 128 * 1024;

    auto stage = [&](int buf, int kv0) {
        const unsigned short* kb = qkv + (size_t)(b * 1024 + kv0) * 3072 + 1024 + h * 128;
#pragma unroll
        for (int cc = 0; cc < 2; cc++) {
            gload16(kb + (size_t)(cc * 32 + krow) * 3072 + ksrc,
                    (void*)(Ks + buf * 8192 + cc * 4096 + tid * 8));
            gload16(vtg + (size_t)(cc * 64 + vrow) * 1024 + kv0 + vsrc,
                    (void*)(Vts + buf * 8192 + cc * 4096 + tid * 8));
        }
    };

    stage(0, 0);
    vmwait0();
    barrier_raw();

#pragma unroll 1
    for (int tile = 0; tile < 16; ++tile) {
        int cur = tile & 1;
        bool more = tile < 15;
        if (more) stage(cur ^ 1, (tile + 1) * 64);
        const __bf16* Kc = Ks + cur * 8192;
        const __bf16* Vc = Vts + cur * 8192;

        f32x4 St[4];
#pragma unroll
        for (int n = 0; n < 4; n++) St[n] = (f32x4){0.f, 0.f, 0.f, 0.f};
        __builtin_amdgcn_s_setprio(1);
#pragma unroll
        for (int ks = 0; ks < 4; ks++) {
#pragma unroll
            for (int n = 0; n < 4; n++) {
                bf16x8 kf = *(const bf16x8*)&Kc[(n * 16 + t) * 128 + (((ks * 64 + g * 16) ^ swzt) >> 1)];
                St[n] = __builtin_amdgcn_mfma_f32_16x16x32_bf16(kf, qf[ks], St[n], 0, 0, 0);
            }
        }
        __builtin_amdgcn_s_setprio(0);

        float mx = -1e30f;
#pragma unroll
        for (int n = 0; n < 4; n++)
#pragma unroll
            for (int r = 0; r < 4; r++) mx = fmaxf(mx, St[n][r]);
        mx *= scale;
        mx = fmaxf(mx, __shfl_xor(mx, 16));
        mx = fmaxf(mx, __shfl_xor(mx, 32));
        if (!__all(mx - m_r <= 8.f)) {
            float mn = fmaxf(m_r, mx);
            float alpha = __expf(m_r - mn);
            m_r = mn;
            l_r *= alpha;
#pragma unroll
            for (int r = 0; r < 4; r++) {
                float ar = __shfl(alpha, (lane & 48) + g * 4 + r);
#pragma unroll
                for (int n2 = 0; n2 < 8; n2++) Oa[n2][r] *= ar;
            }
        }
        float p[4][4];
        float rs = 0.f;
#pragma unroll
        for (int n = 0; n < 4; n++)
#pragma unroll
            for (int r = 0; r < 4; r++) {
                float pv = __expf(St[n][r] * scale - m_r);
                p[n][r] = pv;
                rs += pv;
            }
        rs += __shfl_xor(rs, 16);
        rs += __shfl_xor(rs, 32);
        l_r += rs;

        unsigned P01[4], P23[4];
#pragma unroll
        for (int n = 0; n < 4; n++) {
            P01[n] = (unsigned)f2bf(p[n][0]) | ((unsigned)f2bf(p[n][1]) << 16);
            P23[n] = (unsigned)f2bf(p[n][2]) | ((unsigned)f2bf(p[n][3]) << 16);
        }

#pragma unroll
        for (int ks2 = 0; ks2 < 2; ks2++) {
            int e = ks2 * 2, od = ks2 * 2 + 1;
            unsigned s16a = (g < 2) ? P01[e] : P01[od];
            unsigned s16b = (g < 2) ? P23[e] : P23[od];
            unsigned s32a = (g & 1) ? P01[e] : P01[od];
            unsigned s32b = (g & 1) ? P23[e] : P23[od];
            unsigned s48a = (g >= 2) ? P01[e] : P01[od];
            unsigned s48b = (g >= 2) ? P23[e] : P23[od];
            unsigned r16a = __shfl_xor(s16a, 16), r16b = __shfl_xor(s16b, 16);
            unsigned r32a = __shfl_xor(s32a, 32), r32b = __shfl_xor(s32b, 32);
            unsigned r48a = __shfl_xor(s48a, 48), r48b = __shfl_xor(s48b, 48);
            union { unsigned u[4]; bf16x8 v; } pa;
            pa.u[0] = (g == 0) ? P01[e] : (g == 1) ? r48a : (g == 2) ? r32a : r16a;
            pa.u[1] = (g == 0) ? P23[e] : (g == 1) ? r48b : (g == 2) ? r32b : r16b;
            pa.u[2] = (g == 0) ? r16a : (g == 1) ? r32a : (g == 2) ? r48a : P01[od];
            pa.u[3] = (g == 0) ? r16b : (g == 1) ? r32b : (g == 2) ? r48b : P23[od];
            __builtin_amdgcn_s_setprio(1);
#pragma unroll
            for (int n2 = 0; n2 < 8; n2++) {
                bf16x8 vf = *(const bf16x8*)&Vc[(n2 * 16 + t) * 64 + (((ks2 * 64 + g * 16) ^ swzt) >> 1)];
                Oa[n2] = __builtin_amdgcn_mfma_f32_16x16x32_bf16(pa.v, vf, Oa[n2], 0, 0, 0);
            }
            __builtin_amdgcn_s_setprio(0);
        }

        if (more) {
            vmwait0();
            barrier_raw();
        }
    }

#pragma unroll
    for (int r = 0; r < 4; r++) {
        float lq = __shfl(l_r, (lane & 48) + g * 4 + r);
        float inv = 1.f / lq;
        int orow = q0 + w * 16 + g * 4 + r;
#pragma unroll
        for (int n2 = 0; n2 < 8; n2++)
            o[(size_t)(b * 1024 + orow) * 1024 + h * 128 + n2 * 16 + t] = f2bf(Oa[n2][r] * inv);
    }
}

extern "C" void kernel_launch(void* const* d_in, const int* in_sizes, int n_in,
                              void* d_out, int out_size, void* d_ws, size_t ws_size,
                              hipStream_t stream) {
    const float* x          = (const float*)d_in[0];
    const float* c          = (const float*)d_in[1];
    const float* m_ada_w    = (const float*)d_in[2];
    const float* m_ada_b    = (const float*)d_in[3];
    const float* m_norm_g   = (const float*)d_in[4];
    const float* m_norm_b   = (const float*)d_in[5];
    const float* in_proj_w  = (const float*)d_in[6];
    const float* in_proj_b  = (const float*)d_in[7];
    const float* out_proj_w = (const float*)d_in[8];
    const float* out_proj_b = (const float*)d_in[9];
    const float* f_ada_w    = (const float*)d_in[10];
    const float* f_ada_b    = (const float*)d_in[11];
    const float* f_norm_g   = (const float*)d_in[12];
    const float* f_norm_b   = (const float*)d_in[13];
    const float* w1         = (const float*)d_in[14];
    const float* b1         = (const float*)d_in[15];
    const float* w2         = (const float*)d_in[16];
    const float* b2         = (const float*)d_in[17];
    float* out = (float*)d_out;
    char* ws = (char*)d_ws;

    // ---- workspace layout (max byte used = 109,248,512 = r13's proven footprint) ----
    // h2 spans [42139648, 109248512) => hbuf for the FF phase MUST be outside it.
    unsigned short* Wq    = (unsigned short*)(ws + 0);          // [0, 6291456)         w@1 r@4
    unsigned short* Wo    = (unsigned short*)(ws + 6291456);    // [6291456, 8388608)   w@1 r@6
    unsigned short* vt    = (unsigned short*)(ws + 8388608);    // [8388608, 25165824)  w@4 r@5
    unsigned short* hbuf2 = (unsigned short*)(ws + 8388608);    //   reuse: w@7 r@8 (vt dead)
    unsigned short* W1t   = (unsigned short*)(ws + 25165824);   // [25165824, 33554432) w@1 r@8
    unsigned short* W2t   = (unsigned short*)(ws + 33554432);   // [33554432, 41943040) w@1 r@9
    float*          modm  = (float*)(ws + 41943040);            // [41943040, 42041344) w@2 r@3,6
    float*          modf  = (float*)(ws + 42041344);            // [42041344, 42139648) w@2 r@7,9
    unsigned short* qkv   = (unsigned short*)(ws + 42139648);   // [42139648, 92471296) w@4 r@5
    unsigned short* h2    = (unsigned short*)(ws + 42139648);   // [42139648, 109248512) w@8 r@9
    unsigned short* obuf  = (unsigned short*)(ws + 92471296);   // [92471296, 109248512) w@5 r@6
    unsigned short* hbuf1 = (unsigned short*)(ws + 92471296);   //   w@3 r@4 (obuf overwrites @5)
    float*          part  = (float*)(ws + 92471296);            //   w@1 r@2 (hbuf1 overwrites @3)
    float*          part2 = (float*)(ws + 94044160);

    hipFuncSetAttribute((const void*)&gemm9<0>, hipFuncAttributeMaxDynamicSharedMemorySize, 65536);
    hipFuncSetAttribute((const void*)&gemm9<2>, hipFuncAttributeMaxDynamicSharedMemorySize, 65536);
    hipFuncSetAttribute((const void*)&gemmo<1>, hipFuncAttributeMaxDynamicSharedMemorySize, 32768);
    hipFuncSetAttribute((const void*)&gemmo<3>, hipFuncAttributeMaxDynamicSharedMemorySize, 32768);
    hipFuncSetAttribute((const void*)&attn_kernel, hipFuncAttributeMaxDynamicSharedMemorySize, 65536);

    // 1: all x-independent prep in one launch
    hipLaunchKernelGGL(prep_all, dim3(12672), dim3(256), 0, stream,
                       in_proj_w, out_proj_w, w1, w2, c, m_ada_w, f_ada_w,
                       Wq, Wo, W1t, W2t, part, part2);
    // 2: ada reduce (both branches)
    hipLaunchKernelGGL(ada_reduce, dim3(96, 2), dim3(256), 0, stream,
                       part, part2, m_ada_b, f_ada_b, modm, modf);
    // 3: LN+mod #1 -> hbuf1
    hipLaunchKernelGGL(ln_mod_kernel, dim3(8192), dim3(256), 0, stream, x, m_norm_g, m_norm_b, modm, hbuf1);
    // 4: qkv GEMM (V cols transposed into vt in-epilogue)
    hipLaunchKernelGGL(HIP_KERNEL_NAME(gemm9<0>), dim3(384), dim3(512), 65536, stream,
                       hbuf1, Wq, 3072, 1024, 12, in_proj_b, qkv, vt);
    // 5: attention
    hipLaunchKernelGGL(attn_kernel, dim3(512), dim3(512), 65536, stream, qkv, vt, obuf);
    // 6: out-proj + gated residual
    hipLaunchKernelGGL(HIP_KERNEL_NAME(gemmo<1>), dim3(512), dim3(256), 32768, stream,
                       obuf, Wo, 1024, 1024, 8, out_proj_b, x, modm, out);
    // 7: LN+mod #2 -> hbuf2 (vt region; disjoint from h2)
    hipLaunchKernelGGL(ln_mod_kernel, dim3(8192), dim3(256), 0, stream, out, f_norm_g, f_norm_b, modf, hbuf2);
    // 8: FF1 + gelu (writes h2 over qkv+obuf, both dead; input hbuf2 untouched)
    hipLaunchKernelGGL(HIP_KERNEL_NAME(gemm9<2>), dim3(512), dim3(512), 65536, stream,
                       hbuf2, W1t, 4096, 1024, 16, b1, h2, (unsigned short*)nullptr);
    // 9: FF2 + gated residual accumulate
    hipLaunchKernelGGL(HIP_KERNEL_NAME(gemmo<3>), dim3(512), dim3(256), 32768, stream,
                       h2, W2t, 1024, 4096, 8, b2, (const float*)nullptr, modf, out);
}